// Round 1
// baseline (16587.817 us; speedup 1.0000x reference)
//
#include <hip/hip_runtime.h>
#include <math.h>

#define BATCH 16
#define TLEN 2048
#define NTOK (BATCH*TLEN)       // 32768
#define DMODEL 160
#define DINNER 320
#define DSTATE 64
#define DTRANK 10
#define XDBL 138                // DTRANK + 2*DSTATE
#define DCONV 12
#define PREK 9
#define NBLK 8

__device__ __forceinline__ float sigmoidf_(float x) { return 1.f / (1.f + __expf(-x)); }

// ---------------- pre conv (k=9, same pad) + exact GELU ----------------
__global__ __launch_bounds__(256)
void k_preconv(const float* __restrict__ x, const float* __restrict__ w,
               const float* __restrict__ bias, float* __restrict__ h) {
  int gid = blockIdx.x * 256 + threadIdx.x;
  if (gid >= NTOK * DMODEL) return;
  int c = gid % DMODEL;
  int tok = gid / DMODEL;
  int b = tok / TLEN, t = tok % TLEN;
  const float* xb = x + (size_t)b * TLEN;
  float acc = bias[c];
#pragma unroll
  for (int k = 0; k < PREK; ++k) {
    int tp = t + k - PREK / 2;
    float xv = (tp >= 0 && tp < TLEN) ? xb[tp] : 0.f;
    acc = fmaf(w[c * PREK + k], xv, acc);
  }
  h[gid] = 0.5f * acc * (1.f + erff(acc * 0.70710678118654752440f));
}

// ---------------- LayerNorm over d=160, wave per row ----------------
__global__ __launch_bounds__(256)
void k_ln(const float* __restrict__ h, const float* __restrict__ g,
          const float* __restrict__ bb, float* __restrict__ y) {
  int row = blockIdx.x * 4 + (threadIdx.x >> 6);
  int lane = threadIdx.x & 63;
  const float* hr = h + (size_t)row * DMODEL;
  float v0 = hr[lane], v1 = hr[lane + 64];
  float v2 = (lane < DMODEL - 128) ? hr[lane + 128] : 0.f;
  float s = v0 + v1 + v2;
  float sq = v0 * v0 + v1 * v1 + v2 * v2;
#pragma unroll
  for (int off = 32; off; off >>= 1) {
    s += __shfl_xor(s, off);
    sq += __shfl_xor(sq, off);
  }
  float mean = s * (1.f / DMODEL);
  float var = sq * (1.f / DMODEL) - mean * mean;
  float rstd = rsqrtf(var + 1e-5f);
  float* yr = y + (size_t)row * DMODEL;
  yr[lane] = (v0 - mean) * rstd * g[lane] + bb[lane];
  yr[lane + 64] = (v1 - mean) * rstd * g[lane + 64] + bb[lane + 64];
  if (lane < DMODEL - 128)
    yr[lane + 128] = (v2 - mean) * rstd * g[lane + 128] + bb[lane + 128];
}

// ---------------- fp32 GEMM: C[M,N] = A[M,K] @ W[N,K]^T (+resid) ----------------
// 64x64 tile, 256 threads, 4x4 microtile, BK=16, LDS k-major stride 68.
__global__ __launch_bounds__(256)
void k_gemm(const float* __restrict__ A, const float* __restrict__ W,
            float* __restrict__ C, const float* __restrict__ resid,
            int N, int K) {
  __shared__ float As[16 * 68];
  __shared__ float Ws[16 * 68];
  int tid = threadIdx.x;
  int m0 = blockIdx.y * 64;
  int n0 = blockIdx.x * 64;
  int r = tid >> 2;           // 0..63
  int c4 = (tid & 3) << 2;    // 0,4,8,12
  int tx = tid & 15, ty = tid >> 4;
  const float* Ap = A + (size_t)(m0 + r) * K + c4;
  int wrow = n0 + r;
  bool wv = wrow < N;
  const float* Wp = W + (size_t)(wv ? wrow : 0) * K + c4;
  float4 aR = *(const float4*)Ap;
  float4 wR = *(const float4*)Wp;
  if (!wv) wR = make_float4(0.f, 0.f, 0.f, 0.f);
  float acc[4][4] = {};
  int numK = K >> 4;
  for (int kt = 0; kt < numK; ++kt) {
    As[(c4 + 0) * 68 + r] = aR.x; As[(c4 + 1) * 68 + r] = aR.y;
    As[(c4 + 2) * 68 + r] = aR.z; As[(c4 + 3) * 68 + r] = aR.w;
    Ws[(c4 + 0) * 68 + r] = wR.x; Ws[(c4 + 1) * 68 + r] = wR.y;
    Ws[(c4 + 2) * 68 + r] = wR.z; Ws[(c4 + 3) * 68 + r] = wR.w;
    __syncthreads();
    if (kt + 1 < numK) {
      aR = *(const float4*)(Ap + (size_t)(kt + 1) * 16);
      wR = wv ? *(const float4*)(Wp + (size_t)(kt + 1) * 16)
              : make_float4(0.f, 0.f, 0.f, 0.f);
    }
#pragma unroll
    for (int k = 0; k < 16; ++k) {
      float4 a4 = *(const float4*)&As[k * 68 + (ty << 2)];
      float4 w4 = *(const float4*)&Ws[k * 68 + (tx << 2)];
      float av[4] = {a4.x, a4.y, a4.z, a4.w};
      float wvv[4] = {w4.x, w4.y, w4.z, w4.w};
#pragma unroll
      for (int i = 0; i < 4; ++i)
#pragma unroll
        for (int j = 0; j < 4; ++j)
          acc[i][j] = fmaf(av[i], wvv[j], acc[i][j]);
    }
    __syncthreads();
  }
#pragma unroll
  for (int i = 0; i < 4; ++i) {
    int row = m0 + (ty << 2) + i;
#pragma unroll
    for (int j = 0; j < 4; ++j) {
      int col = n0 + (tx << 2) + j;
      if (col < N) {
        float v = acc[i][j];
        if (resid) v += resid[(size_t)row * N + col];
        C[(size_t)row * N + col] = v;
      }
    }
  }
}

// ---------------- depthwise causal conv (k=12) + SiLU on u; SiLU(z) in place ----------------
__global__ __launch_bounds__(256)
void k_conv(float* __restrict__ xz, const float* __restrict__ cw,
            const float* __restrict__ cb, float* __restrict__ u) {
  int gid = blockIdx.x * 256 + threadIdx.x;
  if (gid >= NTOK * DINNER) return;
  int d = gid % DINNER;
  int tok = gid / DINNER;
  int b = tok / TLEN, t = tok % TLEN;
  const float* ucol = xz + (size_t)b * TLEN * 640 + d;
  float acc = cb[d];
#pragma unroll
  for (int k = 0; k < DCONV; ++k) {
    int tp = t + k - (DCONV - 1);
    if (tp >= 0) acc = fmaf(cw[d * DCONV + k], ucol[(size_t)tp * 640], acc);
  }
  u[gid] = acc * sigmoidf_(acc);
  float* zp = xz + (size_t)tok * 640 + 320 + d;
  float z = *zp;
  *zp = z * sigmoidf_(z);
}

// ---------------- delta = softplus(dt @ dt_w^T + dt_b) ----------------
__global__ __launch_bounds__(256)
void k_dt(const float* __restrict__ xdbl, const float* __restrict__ dw,
          const float* __restrict__ db, float* __restrict__ delta) {
  int gid = blockIdx.x * 256 + threadIdx.x;
  if (gid >= NTOK * DINNER) return;
  int d = gid % DINNER;
  int tok = gid / DINNER;
  const float* row = xdbl + (size_t)tok * XDBL;
  float acc = db[d];
#pragma unroll
  for (int rr = 0; rr < DTRANK; ++rr)
    acc = fmaf(row[rr], dw[d * DTRANK + rr], acc);
  delta[gid] = (acc > 20.f) ? acc : log1pf(__expf(acc));
}

// ---------------- selective scan: wave per (b,d), lane = state ----------------
// dy holds delta on input; y written in place. Epilogue (+u*D)*silu(z) fused.
__global__ __launch_bounds__(256)
void k_scan(const float* __restrict__ u, const float* __restrict__ xz,
            const float* __restrict__ xdbl, const float* __restrict__ Alog,
            const float* __restrict__ Dskip, float* __restrict__ dy) {
  int b = blockIdx.x / (DINNER / 4);
  int dg = blockIdx.x % (DINNER / 4);
  int wave = threadIdx.x >> 6;
  int lane = threadIdx.x & 63;
  int d = dg * 4 + wave;
  float Al = -__expf(Alog[d * DSTATE + lane]);
  float Dd = Dskip[d];
  size_t tokbase = (size_t)b * TLEN;
  const float* pu = u + tokbase * DINNER + d;
  const float* pz = xz + tokbase * 640 + 320 + d;
  const float* pB = xdbl + tokbase * XDBL + DTRANK + lane;
  const float* pC = pB + DSTATE;
  float* pd = dy + tokbase * DINNER + d;
  float h = 0.f;
  for (int t = 0; t < TLEN; ++t) {
    float del = *pd;
    float uu = *pu;
    float zz = *pz;
    float Bv = *pB;
    float Cv = *pC;
    float dA = __expf(del * Al);
    h = fmaf(h, dA, del * uu * Bv);
    float p = h * Cv;
#pragma unroll
    for (int off = 32; off; off >>= 1) p += __shfl_xor(p, off);
    if (lane == 0) {
      float sz = zz * sigmoidf_(zz);
      *pd = (p + uu * Dd) * sz;
    }
    pd += DINNER; pu += DINNER; pz += 640; pB += XDBL; pC += XDBL;
  }
}

// ---------------- head: out[tok] = h[tok,:] . head_w + head_b ----------------
__global__ __launch_bounds__(256)
void k_head(const float* __restrict__ h, const float* __restrict__ hw,
            const float* __restrict__ hb, float* __restrict__ out) {
  int tok = blockIdx.x * 4 + (threadIdx.x >> 6);
  int lane = threadIdx.x & 63;
  const float* hr = h + (size_t)tok * DMODEL;
  float s = hr[lane] * hw[lane] + hr[lane + 64] * hw[lane + 64];
  if (lane < DMODEL - 128) s += hr[lane + 128] * hw[lane + 128];
#pragma unroll
  for (int off = 32; off; off >>= 1) s += __shfl_xor(s, off);
  if (lane == 0) out[tok] = s + hb[0];
}

extern "C" void kernel_launch(void* const* d_in, const int* in_sizes, int n_in,
                              void* d_out, int out_size, void* d_ws, size_t ws_size,
                              hipStream_t stream) {
  const float* x      = (const float*)d_in[0];
  const float* pre_w  = (const float*)d_in[1];
  const float* pre_b  = (const float*)d_in[2];
  const float* ln_g   = (const float*)d_in[3];
  const float* ln_b   = (const float*)d_in[4];
  const float* in_w   = (const float*)d_in[5];
  const float* conv_w = (const float*)d_in[6];
  const float* conv_b = (const float*)d_in[7];
  const float* xproj_w= (const float*)d_in[8];
  const float* dt_w   = (const float*)d_in[9];
  const float* dt_b   = (const float*)d_in[10];
  const float* A_log  = (const float*)d_in[11];
  const float* D_skip = (const float*)d_in[12];
  const float* out_w  = (const float*)d_in[13];
  const float* head_w = (const float*)d_in[14];
  const float* head_b = (const float*)d_in[15];
  float* out = (float*)d_out;

  // workspace layout (floats): h | ln/x_dbl | xz | u | delta(->y)
  float* ws    = (float*)d_ws;
  float* h     = ws;
  float* lnbuf = h     + (size_t)NTOK * DMODEL;   // also reused as x_dbl (138<160)
  float* xz    = lnbuf + (size_t)NTOK * DMODEL;
  float* u     = xz    + (size_t)NTOK * 640;
  float* delta = u     + (size_t)NTOK * DINNER;

  k_preconv<<<NTOK * DMODEL / 256, 256, 0, stream>>>(x, pre_w, pre_b, h);

  for (int L = 0; L < NBLK; ++L) {
    k_ln<<<NTOK / 4, 256, 0, stream>>>(h, ln_g + L * DMODEL, ln_b + L * DMODEL, lnbuf);
    k_gemm<<<dim3(640 / 64, NTOK / 64), 256, 0, stream>>>(
        lnbuf, in_w + (size_t)L * 640 * DMODEL, xz, nullptr, 640, DMODEL);
    k_conv<<<NTOK * DINNER / 256, 256, 0, stream>>>(
        xz, conv_w + (size_t)L * DINNER * DCONV, conv_b + (size_t)L * DINNER, u);
    k_gemm<<<dim3(3, NTOK / 64), 256, 0, stream>>>(
        u, xproj_w + (size_t)L * XDBL * DINNER, lnbuf, nullptr, XDBL, DINNER);
    k_dt<<<NTOK * DINNER / 256, 256, 0, stream>>>(
        lnbuf, dt_w + (size_t)L * DINNER * DTRANK, dt_b + (size_t)L * DINNER, delta);
    k_scan<<<BATCH * (DINNER / 4), 256, 0, stream>>>(
        u, xz, lnbuf, A_log + (size_t)L * DINNER * DSTATE, D_skip + (size_t)L * DINNER, delta);
    k_gemm<<<dim3(3, NTOK / 64), 256, 0, stream>>>(
        delta, out_w + (size_t)L * DMODEL * DINNER, h, h, DMODEL, DINNER);
  }

  k_head<<<NTOK / 4, 256, 0, stream>>>(h, head_w, head_b, out);
}

// Round 3
// 5722.033 us; speedup vs baseline: 2.8989x; 2.8989x over previous
//
#include <hip/hip_runtime.h>
#include <math.h>

#define BATCH 16
#define TLEN 2048
#define NTOK (BATCH*TLEN)       // 32768
#define DMODEL 160
#define DINNER 320
#define DSTATE 64
#define DTRANK 10
#define XDBL 138                // DTRANK + 2*D_STATE
#define DCONV 12
#define PREK 9
#define NBLK 8

__device__ __forceinline__ float sigmoidf_(float x) { return 1.f / (1.f + __expf(-x)); }

// ---------------- pre conv (k=9, same pad) + exact GELU ----------------
__global__ __launch_bounds__(256)
void k_preconv(const float* __restrict__ x, const float* __restrict__ w,
               const float* __restrict__ bias, float* __restrict__ h) {
  int gid = blockIdx.x * 256 + threadIdx.x;
  if (gid >= NTOK * DMODEL) return;
  int c = gid % DMODEL;
  int tok = gid / DMODEL;
  int b = tok / TLEN, t = tok % TLEN;
  const float* xb = x + (size_t)b * TLEN;
  float acc = bias[c];
#pragma unroll
  for (int k = 0; k < PREK; ++k) {
    int tp = t + k - PREK / 2;
    float xv = (tp >= 0 && tp < TLEN) ? xb[tp] : 0.f;
    acc = fmaf(w[c * PREK + k], xv, acc);
  }
  h[gid] = 0.5f * acc * (1.f + erff(acc * 0.70710678118654752440f));
}

// ---------------- LayerNorm over d=160, wave per row ----------------
__global__ __launch_bounds__(256)
void k_ln(const float* __restrict__ h, const float* __restrict__ g,
          const float* __restrict__ bb, float* __restrict__ y) {
  int row = blockIdx.x * 4 + (threadIdx.x >> 6);
  int lane = threadIdx.x & 63;
  const float* hr = h + (size_t)row * DMODEL;
  float v0 = hr[lane], v1 = hr[lane + 64];
  float v2 = (lane < DMODEL - 128) ? hr[lane + 128] : 0.f;
  float s = v0 + v1 + v2;
  float sq = v0 * v0 + v1 * v1 + v2 * v2;
#pragma unroll
  for (int off = 32; off; off >>= 1) {
    s += __shfl_xor(s, off);
    sq += __shfl_xor(sq, off);
  }
  float mean = s * (1.f / DMODEL);
  float var = sq * (1.f / DMODEL) - mean * mean;
  float rstd = rsqrtf(var + 1e-5f);
  float* yr = y + (size_t)row * DMODEL;
  yr[lane] = (v0 - mean) * rstd * g[lane] + bb[lane];
  yr[lane + 64] = (v1 - mean) * rstd * g[lane + 64] + bb[lane + 64];
  if (lane < DMODEL - 128)
    yr[lane + 128] = (v2 - mean) * rstd * g[lane + 128] + bb[lane + 128];
}

// ---- in_proj GEMM: A[M,160] @ W[640,160]^T -> xbuf[tok][320], zbuf[tok][320] ----
__global__ __launch_bounds__(256)
void k_gemm_in(const float* __restrict__ A, const float* __restrict__ W,
               float* __restrict__ xout, float* __restrict__ zout) {
  const int K = 160;
  __shared__ float As[16 * 68];
  __shared__ float Ws[16 * 68];
  int tid = threadIdx.x;
  int m0 = blockIdx.y * 64;
  int n0 = blockIdx.x * 64;
  int r = tid >> 2;
  int c4 = (tid & 3) << 2;
  int tx = tid & 15, ty = tid >> 4;
  const float* Ap = A + (size_t)(m0 + r) * K + c4;
  const float* Wp = W + (size_t)(n0 + r) * K + c4;
  float4 aR = *(const float4*)Ap;
  float4 wR = *(const float4*)Wp;
  float acc[4][4] = {};
  const int numK = K >> 4;  // 10
  for (int kt = 0; kt < numK; ++kt) {
    As[(c4 + 0) * 68 + r] = aR.x; As[(c4 + 1) * 68 + r] = aR.y;
    As[(c4 + 2) * 68 + r] = aR.z; As[(c4 + 3) * 68 + r] = aR.w;
    Ws[(c4 + 0) * 68 + r] = wR.x; Ws[(c4 + 1) * 68 + r] = wR.y;
    Ws[(c4 + 2) * 68 + r] = wR.z; Ws[(c4 + 3) * 68 + r] = wR.w;
    __syncthreads();
    if (kt + 1 < numK) {
      aR = *(const float4*)(Ap + (size_t)(kt + 1) * 16);
      wR = *(const float4*)(Wp + (size_t)(kt + 1) * 16);
    }
#pragma unroll
    for (int k = 0; k < 16; ++k) {
      float4 a4 = *(const float4*)&As[k * 68 + (ty << 2)];
      float4 w4 = *(const float4*)&Ws[k * 68 + (tx << 2)];
      float av[4] = {a4.x, a4.y, a4.z, a4.w};
      float wv[4] = {w4.x, w4.y, w4.z, w4.w};
#pragma unroll
      for (int i = 0; i < 4; ++i)
#pragma unroll
        for (int j = 0; j < 4; ++j)
          acc[i][j] = fmaf(av[i], wv[j], acc[i][j]);
    }
    __syncthreads();
  }
#pragma unroll
  for (int i = 0; i < 4; ++i) {
    int row = m0 + (ty << 2) + i;
#pragma unroll
    for (int j = 0; j < 4; ++j) {
      int col = n0 + (tx << 2) + j;
      if (col < DINNER) xout[(size_t)row * DINNER + col] = acc[i][j];
      else zout[(size_t)row * DINNER + col - DINNER] = acc[i][j];
    }
  }
}

// ------------- GEMM, A time-major At[b][K][TLEN], K=320: C[tok][N] (+resid) -------------
__global__ __launch_bounds__(256)
void k_gemm_at(const float* __restrict__ At, const float* __restrict__ W,
               float* __restrict__ C, const float* __restrict__ resid,
               int N, int K) {
  __shared__ float As[16 * 68];
  __shared__ float Ws[16 * 68];
  int tid = threadIdx.x;
  int m0 = blockIdx.y * 64;
  int n0 = blockIdx.x * 64;
  int b = m0 >> 11, t0 = m0 & (TLEN - 1);
  const float* Ab = At + (size_t)b * K * TLEN + t0;
  int r = tid >> 2;
  int c4 = (tid & 3) << 2;
  int tx = tid & 15, ty = tid >> 4;
  int ar = tid >> 6, am = tid & 63;
  int wrow = n0 + r;
  bool wv = wrow < N;
  const float* Wp = W + (size_t)(wv ? wrow : 0) * K + c4;
  float4 wR = wv ? *(const float4*)Wp : make_float4(0.f, 0.f, 0.f, 0.f);
  float aR[4];
#pragma unroll
  for (int i = 0; i < 4; ++i)
    aR[i] = Ab[(size_t)(ar + 4 * i) * TLEN + am];
  float acc[4][4] = {};
  int numK = K >> 4;
  for (int kt = 0; kt < numK; ++kt) {
#pragma unroll
    for (int i = 0; i < 4; ++i)
      As[(ar + 4 * i) * 68 + am] = aR[i];
    Ws[(c4 + 0) * 68 + r] = wR.x; Ws[(c4 + 1) * 68 + r] = wR.y;
    Ws[(c4 + 2) * 68 + r] = wR.z; Ws[(c4 + 3) * 68 + r] = wR.w;
    __syncthreads();
    if (kt + 1 < numK) {
#pragma unroll
      for (int i = 0; i < 4; ++i)
        aR[i] = Ab[(size_t)((kt + 1) * 16 + ar + 4 * i) * TLEN + am];
      wR = wv ? *(const float4*)(Wp + (size_t)(kt + 1) * 16)
              : make_float4(0.f, 0.f, 0.f, 0.f);
    }
#pragma unroll
    for (int k = 0; k < 16; ++k) {
      float4 a4 = *(const float4*)&As[k * 68 + (ty << 2)];
      float4 w4 = *(const float4*)&Ws[k * 68 + (tx << 2)];
      float av[4] = {a4.x, a4.y, a4.z, a4.w};
      float wv4[4] = {w4.x, w4.y, w4.z, w4.w};
#pragma unroll
      for (int i = 0; i < 4; ++i)
#pragma unroll
        for (int j = 0; j < 4; ++j)
          acc[i][j] = fmaf(av[i], wv4[j], acc[i][j]);
    }
    __syncthreads();
  }
#pragma unroll
  for (int i = 0; i < 4; ++i) {
    int row = m0 + (ty << 2) + i;
#pragma unroll
    for (int j = 0; j < 4; ++j) {
      int col = n0 + (tx << 2) + j;
      if (col < N) {
        float v = acc[i][j];
        if (resid) v += resid[(size_t)row * N + col];
        C[(size_t)row * N + col] = v;
      }
    }
  }
}

// ---- depthwise causal conv (k=12) + SiLU, xbuf[tok][d] -> uT[b][d][t] (LDS transpose) ----
__global__ __launch_bounds__(256)
void k_convT(const float* __restrict__ xbuf, const float* __restrict__ cw,
             const float* __restrict__ cb, float* __restrict__ uT) {
  int t0 = blockIdx.x * 64, d0 = blockIdx.y * 64, b = blockIdx.z;
  __shared__ float xs[76 * 65];
  __shared__ float us[64 * 65];
  int tid = threadIdx.x, j = tid & 63, w = tid >> 6;
#pragma unroll
  for (int it = 0; it < 19; ++it) {
    int r = it * 4 + w;                 // 0..75
    int t = t0 - (DCONV - 1) + r;
    xs[r * 65 + j] = (t >= 0 && t < TLEN)
        ? xbuf[((size_t)b * TLEN + t) * DINNER + d0 + j] : 0.f;
  }
  __syncthreads();
  float cwr[DCONV];
#pragma unroll
  for (int k = 0; k < DCONV; ++k) cwr[k] = cw[(d0 + j) * DCONV + k];
  float cbv = cb[d0 + j];
#pragma unroll
  for (int it = 0; it < 16; ++it) {
    int tl = it * 4 + w;                // 0..63
    float acc = cbv;
#pragma unroll
    for (int k = 0; k < DCONV; ++k)
      acc = fmaf(cwr[k], xs[(tl + k) * 65 + j], acc);
    us[tl * 65 + j] = acc * sigmoidf_(acc);
  }
  __syncthreads();
#pragma unroll
  for (int it = 0; it < 16; ++it) {
    int dl = it * 4 + w;
    uT[((size_t)b * DINNER + d0 + dl) * TLEN + t0 + j] = us[j * 65 + dl];
  }
}

// ---- pack: delT = softplus(dt@dtw^T + dtb) time-major; szT = silu(z) time-major ----
__global__ __launch_bounds__(256)
void k_pack(const float* __restrict__ zbuf, const float* __restrict__ xdbl,
            const float* __restrict__ dtw, const float* __restrict__ dtb,
            float* __restrict__ delT, float* __restrict__ szT) {
  int t0 = blockIdx.x * 64, d0 = blockIdx.y * 64, b = blockIdx.z;
  __shared__ float zs[64 * 65];
  __shared__ float xd[64 * 13];
  int tid = threadIdx.x, j = tid & 63, w = tid >> 6;
#pragma unroll
  for (int it = 0; it < 16; ++it) {
    int i = it * 4 + w;
    zs[i * 65 + j] = zbuf[((size_t)b * TLEN + t0 + i) * DINNER + d0 + j];
  }
  {
    int r = tid >> 2, c = tid & 3;
    size_t rowb = ((size_t)b * TLEN + t0 + r) * XDBL;
    for (int cc = c; cc < DTRANK; cc += 4)
      xd[r * 13 + cc] = xdbl[rowb + cc];
  }
  __syncthreads();
#pragma unroll
  for (int it = 0; it < 16; ++it) {
    int dl = it * 4 + w, d = d0 + dl;
    float acc = dtb[d];
    const float* wr = dtw + d * DTRANK;
#pragma unroll
    for (int rr = 0; rr < DTRANK; ++rr)
      acc = fmaf(xd[j * 13 + rr], wr[rr], acc);
    float del = (acc > 20.f) ? acc : log1pf(__expf(acc));
    size_t o = ((size_t)b * DINNER + d) * TLEN + t0 + j;
    delT[o] = del;
    float zv = zs[j * 65 + dl];
    szT[o] = zv * sigmoidf_(zv);
  }
}

// ---------------- selective scan: wave per (b,d), lane = state ----------------
__global__ __launch_bounds__(256)
void k_scan(const float* __restrict__ delT, const float* __restrict__ uT,
            const float* __restrict__ szT, const float* __restrict__ xdbl,
            const float* __restrict__ Alog, const float* __restrict__ Dskip,
            float* __restrict__ yT) {
  int wave = threadIdx.x >> 6, lane = threadIdx.x & 63;
  int b = blockIdx.x / (DINNER / 4);
  int d = (blockIdx.x % (DINNER / 4)) * 4 + wave;
  __shared__ float ps_all[4][16 * 65];
  float* ps = ps_all[wave];
  float Al = -__expf(Alog[d * DSTATE + lane]);
  float Dd = Dskip[d];
  size_t chan = ((size_t)b * DINNER + d) * TLEN;
  const float* pd = delT + chan;
  const float* pu = uT + chan;
  const float* psz = szT + chan;
  float* py = yT + chan;
  const float* xb = xdbl + (size_t)b * TLEN * XDBL + DTRANK + lane;
  float h = 0.f;
  int tl = lane & 15, qq = lane >> 4;
  for (int t0 = 0; t0 < TLEN; t0 += 16) {
#pragma unroll
    for (int t = 0; t < 16; ++t) {
      float del = pd[t0 + t];
      float uu = pu[t0 + t];
      const float* xr = xb + (size_t)(t0 + t) * XDBL;
      float Bv = xr[0], Cv = xr[DSTATE];
      h = fmaf(h, __expf(del * Al), del * uu * Bv);
      ps[t * 65 + lane] = h * Cv;
    }
    __syncthreads();
    float p = 0.f;
#pragma unroll
    for (int i = 0; i < 16; ++i)
      p += ps[tl * 65 + qq * 16 + i];
    p += __shfl_xor(p, 16);
    p += __shfl_xor(p, 32);
    if (lane < 16) {
      int t = t0 + lane;
      py[t] = (p + pu[t] * Dd) * psz[t];
    }
    __syncthreads();
  }
}

// ---------------- head ----------------
__global__ __launch_bounds__(256)
void k_head(const float* __restrict__ h, const float* __restrict__ hw,
            const float* __restrict__ hb, float* __restrict__ out) {
  int tok = blockIdx.x * 4 + (threadIdx.x >> 6);
  int lane = threadIdx.x & 63;
  const float* hr = h + (size_t)tok * DMODEL;
  float s = hr[lane] * hw[lane] + hr[lane + 64] * hw[lane + 64];
  if (lane < DMODEL - 128) s += hr[lane + 128] * hw[lane + 128];
#pragma unroll
  for (int off = 32; off; off >>= 1) s += __shfl_xor(s, off);
  if (lane == 0) out[tok] = s + hb[0];
}

extern "C" void kernel_launch(void* const* d_in, const int* in_sizes, int n_in,
                              void* d_out, int out_size, void* d_ws, size_t ws_size,
                              hipStream_t stream) {
  const float* x      = (const float*)d_in[0];
  const float* pre_w  = (const float*)d_in[1];
  const float* pre_b  = (const float*)d_in[2];
  const float* ln_g   = (const float*)d_in[3];
  const float* ln_b   = (const float*)d_in[4];
  const float* in_w   = (const float*)d_in[5];
  const float* conv_w = (const float*)d_in[6];
  const float* conv_b = (const float*)d_in[7];
  const float* xproj_w= (const float*)d_in[8];
  const float* dt_w   = (const float*)d_in[9];
  const float* dt_b   = (const float*)d_in[10];
  const float* A_log  = (const float*)d_in[11];
  const float* D_skip = (const float*)d_in[12];
  const float* out_w  = (const float*)d_in[13];
  const float* head_w = (const float*)d_in[14];
  const float* head_b = (const float*)d_in[15];
  float* out = (float*)d_out;

  // workspace (floats), total 52.43M floats = 209.7 MB (same as passing R1):
  // h | lnxd | xbuf | zbuf | uT | delT ; szT aliases xbuf, yT aliases zbuf
  float* ws   = (float*)d_ws;
  float* h    = ws;
  float* lnxd = h    + (size_t)NTOK * DMODEL;
  float* xbuf = lnxd + (size_t)NTOK * DMODEL;
  float* zbuf = xbuf + (size_t)NTOK * DINNER;
  float* uT   = zbuf + (size_t)NTOK * DINNER;
  float* delT = uT   + (size_t)NTOK * DINNER;
  float* szT  = xbuf;   // xbuf dead after k_convT
  float* yT   = zbuf;   // zbuf dead after k_pack

  k_preconv<<<NTOK * DMODEL / 256, 256, 0, stream>>>(x, pre_w, pre_b, h);

  for (int L = 0; L < NBLK; ++L) {
    k_ln<<<NTOK / 4, 256, 0, stream>>>(h, ln_g + L * DMODEL, ln_b + L * DMODEL, lnxd);
    k_gemm_in<<<dim3(10, NTOK / 64), 256, 0, stream>>>(
        lnxd, in_w + (size_t)L * 640 * DMODEL, xbuf, zbuf);
    k_convT<<<dim3(TLEN / 64, DINNER / 64, BATCH), 256, 0, stream>>>(
        xbuf, conv_w + (size_t)L * DINNER * DCONV, conv_b + (size_t)L * DINNER, uT);
    k_gemm_at<<<dim3(3, NTOK / 64), 256, 0, stream>>>(
        uT, xproj_w + (size_t)L * XDBL * DINNER, lnxd, nullptr, XDBL, DINNER);
    k_pack<<<dim3(TLEN / 64, DINNER / 64, BATCH), 256, 0, stream>>>(
        zbuf, lnxd, dt_w + (size_t)L * DINNER * DTRANK, dt_b + (size_t)L * DINNER,
        delT, szT);
    k_scan<<<BATCH * (DINNER / 4), 256, 0, stream>>>(
        delT, uT, szT, lnxd, A_log + (size_t)L * DINNER * DSTATE,
        D_skip + (size_t)L * DINNER, yT);
    k_gemm_at<<<dim3(3, NTOK / 64), 256, 0, stream>>>(
        yT, out_w + (size_t)L * DMODEL * DINNER, h, h, DMODEL, DINNER);
  }

  k_head<<<NTOK / 4, 256, 0, stream>>>(h, head_w, head_b, out);
}

// Round 5
// 4079.930 us; speedup vs baseline: 4.0657x; 1.4025x over previous
//
#include <hip/hip_runtime.h>
#include <math.h>

#define BATCH 16
#define TLEN 2048
#define NTOK (BATCH*TLEN)       // 32768
#define DMODEL 160
#define DINNER 320
#define DSTATE 64
#define DTRANK 10
#define XDBL 138                // DTRANK + 2*D_STATE
#define DCONV 12
#define PREK 9
#define NBLK 8

typedef __attribute__((ext_vector_type(8))) short short8;
typedef __attribute__((ext_vector_type(4))) float floatx4;

__device__ __forceinline__ float sigmoidf_(float x) { return 1.f / (1.f + __expf(-x)); }
__device__ __forceinline__ unsigned short f2bf(float f) {
  union { float f; unsigned u; } v; v.f = f;
  unsigned r = v.u + 0x7FFF + ((v.u >> 16) & 1);   // round-to-nearest-even
  return (unsigned short)(r >> 16);
}

// ---------------- pre conv (k=9, same pad) + exact GELU ----------------
__global__ __launch_bounds__(256)
void k_preconv(const float* __restrict__ x, const float* __restrict__ w,
               const float* __restrict__ bias, float* __restrict__ h) {
  int gid = blockIdx.x * 256 + threadIdx.x;
  if (gid >= NTOK * DMODEL) return;
  int c = gid % DMODEL;
  int tok = gid / DMODEL;
  int b = tok / TLEN, t = tok % TLEN;
  const float* xb = x + (size_t)b * TLEN;
  float acc = bias[c];
#pragma unroll
  for (int k = 0; k < PREK; ++k) {
    int tp = t + k - PREK / 2;
    float xv = (tp >= 0 && tp < TLEN) ? xb[tp] : 0.f;
    acc = fmaf(w[c * PREK + k], xv, acc);
  }
  h[gid] = 0.5f * acc * (1.f + erff(acc * 0.70710678118654752440f));
}

// ---------------- per-layer weight cast to bf16 ----------------
__global__ __launch_bounds__(256)
void k_cast(const float* __restrict__ iw, const float* __restrict__ xw,
            const float* __restrict__ ow, unsigned short* __restrict__ wbf) {
  int i = blockIdx.x * 256 + threadIdx.x;
  if (i < 102400) wbf[i] = f2bf(iw[i]);
  else if (i < 146560) wbf[i] = f2bf(xw[i - 102400]);
  else if (i < 197760) wbf[i] = f2bf(ow[i - 146560]);
}

// ---------------- LayerNorm over d=160 -> bf16 out ----------------
__global__ __launch_bounds__(256)
void k_ln(const float* __restrict__ h, const float* __restrict__ g,
          const float* __restrict__ bb, unsigned short* __restrict__ y) {
  int row = blockIdx.x * 4 + (threadIdx.x >> 6);
  int lane = threadIdx.x & 63;
  const float* hr = h + (size_t)row * DMODEL;
  float v0 = hr[lane], v1 = hr[lane + 64];
  float v2 = (lane < DMODEL - 128) ? hr[lane + 128] : 0.f;
  float s = v0 + v1 + v2;
  float sq = v0 * v0 + v1 * v1 + v2 * v2;
#pragma unroll
  for (int off = 32; off; off >>= 1) {
    s += __shfl_xor(s, off);
    sq += __shfl_xor(sq, off);
  }
  float mean = s * (1.f / DMODEL);
  float var = sq * (1.f / DMODEL) - mean * mean;
  float rstd = rsqrtf(var + 1e-5f);
  unsigned short* yr = y + (size_t)row * DMODEL;
  yr[lane] = f2bf((v0 - mean) * rstd * g[lane] + bb[lane]);
  yr[lane + 64] = f2bf((v1 - mean) * rstd * g[lane + 64] + bb[lane + 64]);
  if (lane < DMODEL - 128)
    yr[lane + 128] = f2bf((v2 - mean) * rstd * g[lane + 128] + bb[lane + 128]);
}

// ------- in_proj MFMA GEMM: A_bf[M,160] @ W_bf[640,160]^T -> xbuf/zbuf fp32 -------
// 128x128 tile, 4 waves (2x2 of 64x64), 16x16x32 bf16 MFMA, K=160 (5 ksteps).
// Staging: each thread loads 16 contiguous bf16 (2x uint4) per kstep.
__global__ __launch_bounds__(256)
void k_mm_in(const unsigned short* __restrict__ A, const unsigned short* __restrict__ Wb,
             float* __restrict__ xout, float* __restrict__ zout) {
  __shared__ short As[128 * 40];
  __shared__ short Ws[128 * 40];
  int tid = threadIdx.x;
  int m0 = blockIdx.y * 128, n0 = blockIdx.x * 128;
  int w = tid >> 6, lane = tid & 63;
  int rm = (w >> 1) * 64, cn = (w & 1) * 64;
  int lm = lane & 15, quad = lane >> 4;
  int r = tid >> 1, seg = tid & 1;     // row 0..127, 16-col half
  const unsigned short* pA = A + (size_t)(m0 + r) * DMODEL + seg * 16;
  const unsigned short* pW = Wb + (size_t)(n0 + r) * DMODEL + seg * 16;
  floatx4 acc[4][4];
#pragma unroll
  for (int i = 0; i < 4; ++i)
#pragma unroll
    for (int j = 0; j < 4; ++j)
      acc[i][j] = (floatx4){0.f, 0.f, 0.f, 0.f};
  for (int kt = 0; kt < 5; ++kt) {
    uint4 a0 = *(const uint4*)(pA + kt * 32);
    uint4 a1 = *(const uint4*)(pA + kt * 32 + 8);
    uint4 w0 = *(const uint4*)(pW + kt * 32);
    uint4 w1 = *(const uint4*)(pW + kt * 32 + 8);
    *(short8*)&As[r * 40 + seg * 16]     = *(short8*)&a0;
    *(short8*)&As[r * 40 + seg * 16 + 8] = *(short8*)&a1;
    *(short8*)&Ws[r * 40 + seg * 16]     = *(short8*)&w0;
    *(short8*)&Ws[r * 40 + seg * 16 + 8] = *(short8*)&w1;
    __syncthreads();
    short8 af[4], wf[4];
#pragma unroll
    for (int i = 0; i < 4; ++i)
      af[i] = *(short8*)&As[(rm + i * 16 + lm) * 40 + quad * 8];
#pragma unroll
    for (int j = 0; j < 4; ++j)
      wf[j] = *(short8*)&Ws[(cn + j * 16 + lm) * 40 + quad * 8];
#pragma unroll
    for (int i = 0; i < 4; ++i)
#pragma unroll
      for (int j = 0; j < 4; ++j)
        acc[i][j] = __builtin_amdgcn_mfma_f32_16x16x32_bf16(af[i], wf[j], acc[i][j], 0, 0, 0);
    __syncthreads();
  }
#pragma unroll
  for (int i = 0; i < 4; ++i)
#pragma unroll
    for (int reg = 0; reg < 4; ++reg) {
      int m = m0 + rm + i * 16 + quad * 4 + reg;
#pragma unroll
      for (int j = 0; j < 4; ++j) {
        int n = n0 + cn + j * 16 + lm;
        float v = acc[i][j][reg];
        if (n < DINNER) xout[(size_t)m * DINNER + n] = v;
        else zout[(size_t)m * DINNER + n - DINNER] = v;
      }
    }
}

// ------- generic MFMA GEMM: A_bf[M,K] @ W_bf[N,K]^T (+resid) -> C fp32 [M,N] -------
// 128x64 tile, 4 waves (each 32x64), runtime N (edge-guarded), K multiple of 32.
__global__ __launch_bounds__(256)
void k_mm_g(const unsigned short* __restrict__ A, const unsigned short* __restrict__ Wb,
            float* __restrict__ C, const float* __restrict__ resid, int N, int K) {
  __shared__ short As[128 * 40];
  __shared__ short Ws[64 * 40];
  int tid = threadIdx.x;
  int m0 = blockIdx.y * 128, n0 = blockIdx.x * 64;
  int w = tid >> 6, lane = tid & 63;
  int rm = w * 32;
  int lm = lane & 15, quad = lane >> 4;
  int r = tid >> 1, seg = tid & 1;     // A: row 0..127, 16-col half
  int wr = tid >> 2, wseg = tid & 3;   // W: row 0..63, 8-col quarter
  bool wvld = (n0 + wr) < N;
  const unsigned short* pA = A + (size_t)(m0 + r) * K + seg * 16;
  const unsigned short* pW = Wb + (size_t)(wvld ? (n0 + wr) : 0) * K + wseg * 8;
  floatx4 acc[2][4];
#pragma unroll
  for (int i = 0; i < 2; ++i)
#pragma unroll
    for (int j = 0; j < 4; ++j)
      acc[i][j] = (floatx4){0.f, 0.f, 0.f, 0.f};
  int nk = K >> 5;
  for (int kt = 0; kt < nk; ++kt) {
    uint4 a0 = *(const uint4*)(pA + kt * 32);
    uint4 a1 = *(const uint4*)(pA + kt * 32 + 8);
    uint4 wv = wvld ? *(const uint4*)(pW + kt * 32)
                    : make_uint4(0u, 0u, 0u, 0u);
    *(short8*)&As[r * 40 + seg * 16]     = *(short8*)&a0;
    *(short8*)&As[r * 40 + seg * 16 + 8] = *(short8*)&a1;
    *(short8*)&Ws[wr * 40 + wseg * 8]    = *(short8*)&wv;
    __syncthreads();
    short8 af[2], wf[4];
#pragma unroll
    for (int i = 0; i < 2; ++i)
      af[i] = *(short8*)&As[(rm + i * 16 + lm) * 40 + quad * 8];
#pragma unroll
    for (int j = 0; j < 4; ++j)
      wf[j] = *(short8*)&Ws[(j * 16 + lm) * 40 + quad * 8];
#pragma unroll
    for (int i = 0; i < 2; ++i)
#pragma unroll
      for (int j = 0; j < 4; ++j)
        acc[i][j] = __builtin_amdgcn_mfma_f32_16x16x32_bf16(af[i], wf[j], acc[i][j], 0, 0, 0);
    __syncthreads();
  }
#pragma unroll
  for (int i = 0; i < 2; ++i)
#pragma unroll
    for (int reg = 0; reg < 4; ++reg) {
      int m = m0 + rm + i * 16 + quad * 4 + reg;
#pragma unroll
      for (int j = 0; j < 4; ++j) {
        int n = n0 + j * 16 + lm;
        if (n < N) {
          float v = acc[i][j][reg];
          if (resid) v += resid[(size_t)m * N + n];
          C[(size_t)m * N + n] = v;
        }
      }
    }
}

// ---- depthwise causal conv (k=12) + SiLU: xbuf[tok][d] -> uT[b][d][t] fp32 + u_bf[tok][d] bf16 ----
__global__ __launch_bounds__(256)
void k_convT(const float* __restrict__ xbuf, const float* __restrict__ cw,
             const float* __restrict__ cb, float* __restrict__ uT,
             unsigned short* __restrict__ ubf) {
  int t0 = blockIdx.x * 64, d0 = blockIdx.y * 64, b = blockIdx.z;
  __shared__ float xs[76 * 65];
  __shared__ float us[64 * 65];
  int tid = threadIdx.x, j = tid & 63, w = tid >> 6;
#pragma unroll
  for (int it = 0; it < 19; ++it) {
    int r = it * 4 + w;                 // 0..75
    int t = t0 - (DCONV - 1) + r;
    xs[r * 65 + j] = (t >= 0 && t < TLEN)
        ? xbuf[((size_t)b * TLEN + t) * DINNER + d0 + j] : 0.f;
  }
  __syncthreads();
  float cwr[DCONV];
#pragma unroll
  for (int k = 0; k < DCONV; ++k) cwr[k] = cw[(d0 + j) * DCONV + k];
  float cbv = cb[d0 + j];
#pragma unroll
  for (int it = 0; it < 16; ++it) {
    int tl = it * 4 + w;                // 0..63
    float acc = cbv;
#pragma unroll
    for (int k = 0; k < DCONV; ++k)
      acc = fmaf(cwr[k], xs[(tl + k) * 65 + j], acc);
    us[tl * 65 + j] = acc * sigmoidf_(acc);
  }
  __syncthreads();
#pragma unroll
  for (int it = 0; it < 16; ++it) {
    int tr = it * 4 + w;
    ubf[((size_t)b * TLEN + t0 + tr) * DINNER + d0 + j] = f2bf(us[tr * 65 + j]);
  }
#pragma unroll
  for (int it = 0; it < 16; ++it) {
    int dl = it * 4 + w;
    uT[((size_t)b * DINNER + d0 + dl) * TLEN + t0 + j] = us[j * 65 + dl];
  }
}

// ---- pack: delT = softplus(dt@dtw^T + dtb) time-major; szT = silu(z) time-major ----
__global__ __launch_bounds__(256)
void k_pack(const float* __restrict__ zbuf, const float* __restrict__ xdbl,
            const float* __restrict__ dtw, const float* __restrict__ dtb,
            float* __restrict__ delT, float* __restrict__ szT) {
  int t0 = blockIdx.x * 64, d0 = blockIdx.y * 64, b = blockIdx.z;
  __shared__ float zs[64 * 65];
  __shared__ float xd[64 * 13];
  int tid = threadIdx.x, j = tid & 63, w = tid >> 6;
#pragma unroll
  for (int it = 0; it < 16; ++it) {
    int i = it * 4 + w;
    zs[i * 65 + j] = zbuf[((size_t)b * TLEN + t0 + i) * DINNER + d0 + j];
  }
  {
    int r = tid >> 2, c = tid & 3;
    size_t rowb = ((size_t)b * TLEN + t0 + r) * XDBL;
    for (int cc = c; cc < DTRANK; cc += 4)
      xd[r * 13 + cc] = xdbl[rowb + cc];
  }
  __syncthreads();
#pragma unroll
  for (int it = 0; it < 16; ++it) {
    int dl = it * 4 + w, d = d0 + dl;
    float acc = dtb[d];
    const float* wr = dtw + d * DTRANK;
#pragma unroll
    for (int rr = 0; rr < DTRANK; ++rr)
      acc = fmaf(xd[j * 13 + rr], wr[rr], acc);
    float del = (acc > 20.f) ? acc : log1pf(__expf(acc));
    size_t o = ((size_t)b * DINNER + d) * TLEN + t0 + j;
    delT[o] = del;
    float zv = zs[j * 65 + dl];
    szT[o] = zv * sigmoidf_(zv);
  }
}

// ---------------- selective scan: wave per (b,d), lane = state; no barriers ----------------
__global__ __launch_bounds__(256)
void k_scan(const float* __restrict__ delT, const float* __restrict__ uT,
            const float* __restrict__ szT, const float* __restrict__ xdbl,
            const float* __restrict__ Alog, const float* __restrict__ Dskip,
            float* __restrict__ yT) {
  int wave = threadIdx.x >> 6, lane = threadIdx.x & 63;
  int b = blockIdx.x / (DINNER / 4);
  int d = (blockIdx.x % (DINNER / 4)) * 4 + wave;
  __shared__ float ps_all[4][16 * 65];
  float* ps = ps_all[wave];               // per-wave region; same-wave DS ops are ordered
  float Al = -__expf(Alog[d * DSTATE + lane]);
  float Dd = Dskip[d];
  size_t chan = ((size_t)b * DINNER + d) * TLEN;
  const float* pd = delT + chan;
  const float* pu = uT + chan;
  const float* psz = szT + chan;
  float* py = yT + chan;
  const float* xb = xdbl + (size_t)b * TLEN * XDBL + DTRANK + lane;
  float h = 0.f;
  int tl = lane & 15, qq = lane >> 4;
  for (int t0 = 0; t0 < TLEN; t0 += 16) {
#pragma unroll
    for (int t = 0; t < 16; ++t) {
      float del = pd[t0 + t];
      float uu = pu[t0 + t];
      const float* xr = xb + (size_t)(t0 + t) * XDBL;
      float Bv = xr[0], Cv = xr[DSTATE];
      h = fmaf(h, __expf(del * Al), del * uu * Bv);
      ps[t * 65 + lane] = h * Cv;
    }
    float p = 0.f;
#pragma unroll
    for (int i = 0; i < 16; ++i)
      p += ps[tl * 65 + qq * 16 + i];
    p += __shfl_xor(p, 16);
    p += __shfl_xor(p, 32);
    if (lane < 16) {
      int t = t0 + lane;
      py[t] = (p + pu[t] * Dd) * psz[t];
    }
  }
}

// ---- transpose yT[b][d][t] fp32 -> y_bf[tok][d] bf16 ----
__global__ __launch_bounds__(256)
void k_t2b(const float* __restrict__ yT, unsigned short* __restrict__ ybf) {
  int t0 = blockIdx.x * 64, d0 = blockIdx.y * 64, b = blockIdx.z;
  __shared__ float ls[64 * 65];
  int tid = threadIdx.x, j = tid & 63, w = tid >> 6;
#pragma unroll
  for (int it = 0; it < 16; ++it) {
    int dl = it * 4 + w;
    ls[dl * 65 + j] = yT[((size_t)b * DINNER + d0 + dl) * TLEN + t0 + j];
  }
  __syncthreads();
#pragma unroll
  for (int it = 0; it < 16; ++it) {
    int tr = it * 4 + w;
    ybf[((size_t)b * TLEN + t0 + tr) * DINNER + d0 + j] = f2bf(ls[j * 65 + tr]);
  }
}

// ---------------- head ----------------
__global__ __launch_bounds__(256)
void k_head(const float* __restrict__ h, const float* __restrict__ hw,
            const float* __restrict__ hb, float* __restrict__ out) {
  int tok = blockIdx.x * 4 + (threadIdx.x >> 6);
  int lane = threadIdx.x & 63;
  const float* hr = h + (size_t)tok * DMODEL;
  float s = hr[lane] * hw[lane] + hr[lane + 64] * hw[lane + 64];
  if (lane < DMODEL - 128) s += hr[lane + 128] * hw[lane + 128];
#pragma unroll
  for (int off = 32; off; off >>= 1) s += __shfl_xor(s, off);
  if (lane == 0) out[tok] = s + hb[0];
}

extern "C" void kernel_launch(void* const* d_in, const int* in_sizes, int n_in,
                              void* d_out, int out_size, void* d_ws, size_t ws_size,
                              hipStream_t stream) {
  const float* x      = (const float*)d_in[0];
  const float* pre_w  = (const float*)d_in[1];
  const float* pre_b  = (const float*)d_in[2];
  const float* ln_g   = (const float*)d_in[3];
  const float* ln_b   = (const float*)d_in[4];
  const float* in_w   = (const float*)d_in[5];
  const float* conv_w = (const float*)d_in[6];
  const float* conv_b = (const float*)d_in[7];
  const float* xproj_w= (const float*)d_in[8];
  const float* dt_w   = (const float*)d_in[9];
  const float* dt_b   = (const float*)d_in[10];
  const float* A_log  = (const float*)d_in[11];
  const float* D_skip = (const float*)d_in[12];
  const float* out_w  = (const float*)d_in[13];
  const float* head_w = (const float*)d_in[14];
  const float* head_b = (const float*)d_in[15];
  float* out = (float*)d_out;

  // workspace (floats), total 51,806,784 f = 207.2 MB:
  // h | xdbl | R (lnxd_bf -> u_bf -> delT, sequential lifetimes) |
  // xbuf (-> szT -> y_bf) | zbuf (-> yT) | uT | wbf
  float* ws   = (float*)d_ws;
  float* h    = ws;
  float* xdbl = h    + (size_t)NTOK * DMODEL;
  float* R    = xdbl + (size_t)NTOK * XDBL;
  float* xbuf = R    + (size_t)NTOK * DINNER;
  float* zbuf = xbuf + (size_t)NTOK * DINNER;
  float* uT   = zbuf + (size_t)NTOK * DINNER;
  unsigned short* wbf = (unsigned short*)(uT + (size_t)NTOK * DINNER);

  unsigned short* lnxd_bf = (unsigned short*)R;
  unsigned short* u_bf    = (unsigned short*)R;
  float*          delT    = R;
  float*          szT     = xbuf;
  unsigned short* y_bf    = (unsigned short*)xbuf;
  float*          yT      = zbuf;
  unsigned short* w_in    = wbf;
  unsigned short* w_xp    = wbf + 102400;
  unsigned short* w_ou    = wbf + 146560;

  k_preconv<<<NTOK * DMODEL / 256, 256, 0, stream>>>(x, pre_w, pre_b, h);

  for (int L = 0; L < NBLK; ++L) {
    k_cast<<<773, 256, 0, stream>>>(
        in_w + (size_t)L * 640 * DMODEL, xproj_w + (size_t)L * XDBL * DINNER,
        out_w + (size_t)L * DMODEL * DINNER, wbf);
    k_ln<<<NTOK / 4, 256, 0, stream>>>(h, ln_g + L * DMODEL, ln_b + L * DMODEL, lnxd_bf);
    k_mm_in<<<dim3(5, NTOK / 128), 256, 0, stream>>>(lnxd_bf, w_in, xbuf, zbuf);
    k_convT<<<dim3(TLEN / 64, DINNER / 64, BATCH), 256, 0, stream>>>(
        xbuf, conv_w + (size_t)L * DINNER * DCONV, conv_b + (size_t)L * DINNER, uT, u_bf);
    k_mm_g<<<dim3(3, NTOK / 128), 256, 0, stream>>>(u_bf, w_xp, xdbl, nullptr, XDBL, DINNER);
    k_pack<<<dim3(TLEN / 64, DINNER / 64, BATCH), 256, 0, stream>>>(
        zbuf, xdbl, dt_w + (size_t)L * DINNER * DTRANK, dt_b + (size_t)L * DINNER,
        delT, szT);
    k_scan<<<BATCH * (DINNER / 4), 256, 0, stream>>>(
        delT, uT, szT, xdbl, A_log + (size_t)L * DINNER * DSTATE,
        D_skip + (size_t)L * DINNER, yT);
    k_t2b<<<dim3(TLEN / 64, DINNER / 64, BATCH), 256, 0, stream>>>(yT, y_bf);
    k_mm_g<<<dim3(3, NTOK / 128), 256, 0, stream>>>(y_bf, w_ou, h, h, DMODEL, DINNER);
  }

  k_head<<<NTOK / 4, 256, 0, stream>>>(h, head_w, head_b, out);
}